// Round 14
// baseline (140.783 us; speedup 1.0000x reference)
//
#include <hip/hip_runtime.h>
#include <cmath>

typedef unsigned short u16;
typedef unsigned int u32;
typedef __bf16 bf16x8 __attribute__((ext_vector_type(8)));
typedef __bf16 bf16x4 __attribute__((ext_vector_type(4)));
typedef float f32x4 __attribute__((ext_vector_type(4)));

#define S_LEN 2048
#define D_MODEL 2048
#define DK_ 512
#define PM1_OFF 4194304   // offset of pm[1] in floats (1*1*2048*2048)
#define CEXP 0.06375872f  // (1/(sqrt(512)+1e-6)) * log2(e), folded into Q
#define PSPLIT_ELEMS 4194304u   // 32*2048*64 u16 per split partial

__device__ __forceinline__ u16 f2b(float f) {
  u32 u = __float_as_uint(f);
  return (u16)((u + 0x7fffu + ((u >> 16) & 1u)) >> 16);
}

__device__ __forceinline__ void gload_lds16(const void* gp, void* lp) {
  __builtin_amdgcn_global_load_lds(
      (const __attribute__((address_space(1))) void*)gp,
      (__attribute__((address_space(3))) void*)lp, 16, 0, 0);
}

__device__ __forceinline__ void vmcnt0_barrier() {
  asm volatile("s_waitcnt vmcnt(0)" ::: "memory");
  __builtin_amdgcn_s_barrier();
}

// ---------------- fused fp32 -> bf16 cast of x, Wq, Wk, Wv, Wo ----------------
__global__ __launch_bounds__(256) void cast_all_kernel(
    const float* __restrict__ x, const float* __restrict__ wq,
    const float* __restrict__ wk, const float* __restrict__ wv,
    const float* __restrict__ wo,
    u16* __restrict__ xb, u16* __restrict__ wqb, u16* __restrict__ wkb,
    u16* __restrict__ wvb, u16* __restrict__ wob)
{
  long i4 = (long)blockIdx.x * 256 + threadIdx.x;  // vec4 index
  const float* src; u16* dst; long off;
  if (i4 < 1048576)       { src = x;  dst = xb;  off = i4; }
  else if (i4 < 2097152)  { src = wq; dst = wqb; off = i4 - 1048576; }
  else if (i4 < 2359296)  { src = wk; dst = wkb; off = i4 - 2097152; }
  else if (i4 < 2621440)  { src = wv; dst = wvb; off = i4 - 2359296; }
  else                    { src = wo; dst = wob; off = i4 - 2621440; }
  float4 v = *(const float4*)(src + off * 4);
  ushort4 o;
  o.x = f2b(v.x); o.y = f2b(v.y); o.z = f2b(v.z); o.w = f2b(v.w);
  *(ushort4*)(dst + off * 4) = o;
}

// ---------------- GEMM: C = A @ B^T.  A[M,K], B[N,K] bf16 row-major ----------
// Proven structure: tile 64x128, BK=64, depth-2 dbuf, one vmcnt(0)+barrier per
// tile, T2 both-sides swizzle (conflicts==0), T1 XCD-chunked remap.
// EPI 1: fused QKV epilogue; EPI 2: plain fp32 store.
template<int EPI>
__global__ __launch_bounds__(256) void gemm_bt(
    const u16* __restrict__ A, const u16* __restrict__ B,
    void* __restrict__ C0, void* __restrict__ C1, void* __restrict__ C2,
    int M, int N, int K, const float* __restrict__ pm)
{
  __shared__ u16 As[2][64 * 64];
  __shared__ u16 Bs[2][128 * 64];
  const int tid = threadIdx.x;
  const int lane = tid & 63, w = tid >> 6;
  const int wr = w >> 1, wc = w & 1;
  const int l15 = lane & 15, l4 = lane >> 4;

  // T1 XCD-chunked remap (gridDim.y == 32 == m-tiles in all uses)
  const int nwg = gridDim.x * gridDim.y;
  const int orig = blockIdx.y * gridDim.x + blockIdx.x;
  const int lin2 = (orig & 7) * (nwg >> 3) + (orig >> 3);
  const int m0 = (lin2 & 31) * 64;       // m-tile fastest within XCD chunk
  const int n0 = (lin2 >> 5) * 128;

  // staging: 256 threads x 16B = 4 KB/issue = 32 rows of 64 u16.
  const int srow = tid >> 3;                        // 0..31
  const int scol = ((tid & 7) ^ (srow & 7)) << 3;   // inverse-swizzled src col
  const int swz = (l15 & 7) << 3;                   // u16 XOR for frag reads
  const int ldsoff = (tid >> 6) << 10;              // wave-uniform base
  const u16* gA = A + (size_t)(m0 + srow) * K + scol;
  const u16* gB = B + (size_t)(n0 + srow) * K + scol;

  const f32x4 z4 = {0.f, 0.f, 0.f, 0.f};
  f32x4 acc[2][4];
#pragma unroll
  for (int i = 0; i < 2; ++i)
#pragma unroll
    for (int j = 0; j < 4; ++j) acc[i][j] = z4;

  // prologue: stage tile 0
  {
    char* la = (char*)As[0] + ldsoff;
    char* lb = (char*)Bs[0] + ldsoff;
#pragma unroll
    for (int i = 0; i < 2; ++i) gload_lds16(gA + (size_t)(i * 32) * K, la + i * 4096);
#pragma unroll
    for (int i = 0; i < 4; ++i) gload_lds16(gB + (size_t)(i * 32) * K, lb + i * 4096);
  }
  vmcnt0_barrier();

  const int NT = K >> 6;
  int cur = 0;
  for (int t = 0; t < NT; ++t) {
    if (t + 1 < NT) {  // stage next tile into the other buffer
      const int kt = (t + 1) << 6;
      char* la = (char*)As[cur ^ 1] + ldsoff;
      char* lb = (char*)Bs[cur ^ 1] + ldsoff;
#pragma unroll
      for (int i = 0; i < 2; ++i) gload_lds16(gA + (size_t)(i * 32) * K + kt, la + i * 4096);
#pragma unroll
      for (int i = 0; i < 4; ++i) gload_lds16(gB + (size_t)(i * 32) * K + kt, lb + i * 4096);
    }
    const u16* as = As[cur];
    const u16* bs = Bs[cur];
#pragma unroll
    for (int ks = 0; ks < 2; ++ks) {
      bf16x8 a[2], b[4];
#pragma unroll
      for (int mt = 0; mt < 2; ++mt)
        a[mt] = *(const bf16x8*)(&as[(wr * 32 + mt * 16 + l15) * 64 + ((ks * 32 + l4 * 8) ^ swz)]);
#pragma unroll
      for (int nt = 0; nt < 4; ++nt)
        b[nt] = *(const bf16x8*)(&bs[(wc * 64 + nt * 16 + l15) * 64 + ((ks * 32 + l4 * 8) ^ swz)]);
#pragma unroll
      for (int mt = 0; mt < 2; ++mt)
#pragma unroll
        for (int nt = 0; nt < 4; ++nt)
          acc[mt][nt] = __builtin_amdgcn_mfma_f32_16x16x32_bf16(a[mt], b[nt], acc[mt][nt], 0, 0, 0);
    }
    vmcnt0_barrier();   // next tile landed, all waves done reading cur
    cur ^= 1;
  }

#pragma unroll
  for (int mt = 0; mt < 2; ++mt)
#pragma unroll
    for (int nt = 0; nt < 4; ++nt) {
      const int mb = m0 + wr * 32 + mt * 16 + l4 * 4;   // base m (j = 0..3)
      const int n = n0 + wc * 64 + nt * 16 + l15;
      if (EPI == 2) {
#pragma unroll
        for (int j = 0; j < 4; ++j)
          ((float*)C0)[(size_t)(mb + j) * N + n] = acc[mt][nt][j];
      } else if (n >= 2560) {        // V range: write transposed -> xvt[c][m]
        const int c = n - 2560;
        ushort4 q;
        q.x = f2b(acc[mt][nt][0]); q.y = f2b(acc[mt][nt][1]);
        q.z = f2b(acc[mt][nt][2]); q.w = f2b(acc[mt][nt][3]);
        *(ushort4*)((u16*)C2 + (size_t)c * S_LEN + mb) = q;
      } else if (n < 2048) {         // Q range, rope d=2048, fold CEXP
        const int jj = (n < 1024) ? (n + 1024) : (n - 1024);
#pragma unroll
        for (int j = 0; j < 4; ++j) {
          const int m = mb + j;
          const float sv = (n < 1024) ? acc[mt][nt][j] : -acc[mt][nt][j];
          const float p = pm[(size_t)m * D_MODEL + jj] +
                          pm[PM1_OFF + (size_t)m * D_MODEL + jj];
          ((u16*)C0)[(size_t)m * D_MODEL + jj] = f2b(sv * p * CEXP);
        }
      } else {                       // K range, rope d=512
        const int nn = n - 2048;
        const int jj = (nn < 256) ? (nn + 256) : (nn - 256);
#pragma unroll
        for (int j = 0; j < 4; ++j) {
          const int m = mb + j;
          const float sv = (nn < 256) ? acc[mt][nt][j] : -acc[mt][nt][j];
          const float p = pm[(size_t)m * D_MODEL + jj] +
                          pm[PM1_OFF + (size_t)m * D_MODEL + jj];
          ((u16*)C1)[(size_t)m * DK_ + jj] = f2b(sv * p);
        }
      }
    }
}

// ---------------- fused attention, KV-SPLIT partial (swapped QK^T) -----------
// Each block: 32 q/wave x 4 waves = 128 q rows, ONE KV half (split =
// blockIdx.z, 16 tiles of 64). No max-subtraction -> partials combine
// linearly: out = (o0+o1)/(d0+d1+1) in combine_kernel.
// Writes: P partial [split][h][q][64] bf16, DN partial [split][h][q] f32.
// Grid (16,32,2) = 1024 blocks -> 3 blocks/CU (48KB LDS) = 12 waves/CU.
__global__ __launch_bounds__(256) void attn_kernel(
    const u16* __restrict__ Q, const u16* __restrict__ Kx,
    const u16* __restrict__ Vt, u16* __restrict__ P, float* __restrict__ DN)
{
  __shared__ u16 Ks[2][64 * 64];     // K tile [t][hd] swizzled, dbuf (16 KB)
  __shared__ u16 Vs[2][64 * 64];     // V^T tile [hd][t] swizzled, dbuf (16 KB)
  __shared__ u16 Es[4 * 32 * 64];    // per-wave P tile [q][t] swizzled (16 KB)

  const int tid = threadIdx.x;
  const int lane = tid & 63, w = tid >> 6;
  const int l15 = lane & 15, l4 = lane >> 4;

  // T1 XCD-chunked remap per split-plane: h-major, q-block fastest
  const int orig = blockIdx.y * 16 + blockIdx.x;
  const int lin2 = (orig & 7) * 64 + (orig >> 3);
  const int h = lin2 >> 4;
  const int qb = lin2 & 15;
  const int q0 = qb * 128 + w * 32;  // wave's 32-row base
  const int hk = (h & 7) * 64;       // kv column base (GQA: kv head = h%8)
  const int split = blockIdx.z;
  const int tbase = split << 10;     // this block's KV range: [tbase, tbase+1024)

  // Q as B-operand, two 16-row groups: row q = q0 + g*16 + l15
  bf16x8 bq[2][2];
#pragma unroll
  for (int g = 0; g < 2; ++g)
#pragma unroll
    for (int ks = 0; ks < 2; ++ks)
      bq[g][ks] = *(const bf16x8*)(Q + (size_t)(q0 + g * 16 + l15) * D_MODEL
                                     + h * 64 + ks * 32 + l4 * 8);

  bf16x8 b1;   // all-ones B fragment for the denominator MFMA
#pragma unroll
  for (int i = 0; i < 8; ++i) b1[i] = (__bf16)1.0f;

  const f32x4 z4 = {0.f, 0.f, 0.f, 0.f};
  f32x4 o[2][4], dsum[2];
#pragma unroll
  for (int g = 0; g < 2; ++g) {
    dsum[g] = z4;
#pragma unroll
    for (int nt = 0; nt < 4; ++nt) o[g][nt] = z4;
  }

  u16* Ew = Es + w * (32 * 64);
  const int swz = (l15 & 7) << 3;                    // u16 XOR for frag reads
  const int srow = tid >> 3;                         // staging row 0..31
  const int scol = ((tid & 7) ^ (srow & 7)) << 3;    // inverse-swizzled src col
  const int ldsoff = w << 10;                        // wave-uniform LDS base
  const u16* gK = Kx + (size_t)srow * DK_ + hk + scol;
  const u16* gV = Vt + (size_t)(hk + srow) * S_LEN + scol;

  // prologue: stage tile tbase
  {
    char* lK = (char*)Ks[0] + ldsoff;
    char* lV = (char*)Vs[0] + ldsoff;
    gload_lds16(gK + (size_t)tbase * DK_,             lK);
    gload_lds16(gK + (size_t)(tbase + 32) * DK_,      lK + 4096);
    gload_lds16(gV + tbase,                           lV);
    gload_lds16(gV + tbase + (size_t)32 * S_LEN,      lV + 4096);
  }
  vmcnt0_barrier();

  int cur = 0;
  const int tend = tbase + 1024;
  for (int t0 = tbase; t0 < tend; t0 += 64) {
    if (t0 + 64 < tend) {  // stage next KV tile
      char* lK = (char*)Ks[cur ^ 1] + ldsoff;
      char* lV = (char*)Vs[cur ^ 1] + ldsoff;
      gload_lds16(gK + (size_t)(t0 + 64) * DK_,       lK);
      gload_lds16(gK + (size_t)(t0 + 96) * DK_,       lK + 4096);
      gload_lds16(gV + t0 + 64,                       lV);
      gload_lds16(gV + t0 + 64 + (size_t)32 * S_LEN,  lV + 4096);
    }
    const u16* ks_ = Ks[cur];
    const u16* vs_ = Vs[cur];

    // swapped QK^T: sT[g][tf] = K-rows x Q-rows(group g); ak read ONCE per ks
    f32x4 sT[2][4];
#pragma unroll
    for (int g = 0; g < 2; ++g)
#pragma unroll
      for (int tf = 0; tf < 4; ++tf) sT[g][tf] = z4;
#pragma unroll
    for (int ks = 0; ks < 2; ++ks) {
      bf16x8 ak[4];
#pragma unroll
      for (int tf = 0; tf < 4; ++tf)
        ak[tf] = *(const bf16x8*)(&ks_[(tf * 16 + l15) * 64 + ((ks * 32 + l4 * 8) ^ swz)]);
      __builtin_amdgcn_s_setprio(1);
#pragma unroll
      for (int g = 0; g < 2; ++g)
#pragma unroll
        for (int tf = 0; tf < 4; ++tf)
          sT[g][tf] = __builtin_amdgcn_mfma_f32_16x16x32_bf16(ak[tf], bq[g][ks], sT[g][tf], 0, 0, 0);
      __builtin_amdgcn_s_setprio(0);
    }

    // exp (raw v_exp_f32) + packed P staging. lane holds q = q0+g*16+l15;
    // t = tf*16 + l4*4 + j (local). Row (g*16+l15) swizzle uses (l15&7).
#pragma unroll
    for (int g = 0; g < 2; ++g)
#pragma unroll
      for (int tf = 0; tf < 4; ++tf) {
        const float e0 = __builtin_amdgcn_exp2f(sT[g][tf][0]);
        const float e1 = __builtin_amdgcn_exp2f(sT[g][tf][1]);
        const float e2 = __builtin_amdgcn_exp2f(sT[g][tf][2]);
        const float e3 = __builtin_amdgcn_exp2f(sT[g][tf][3]);
        bf16x4 pk = {(__bf16)e0, (__bf16)e1, (__bf16)e2, (__bf16)e3};
        *(bf16x4*)(&Ew[(g * 16 + l15) * 64 + ((tf * 16 + l4 * 4) ^ swz)]) = pk;
      }

    // PV: o[g][nt] += P[q,t] @ V[t,hd]; dsum[g] += P @ ones.
#pragma unroll
    for (int ks = 0; ks < 2; ++ks) {
      bf16x8 ae[2], bv[4];
#pragma unroll
      for (int g = 0; g < 2; ++g)
        ae[g] = *(const bf16x8*)(&Ew[(g * 16 + l15) * 64 + ((ks * 32 + l4 * 8) ^ swz)]);
#pragma unroll
      for (int nt = 0; nt < 4; ++nt)
        bv[nt] = *(const bf16x8*)(&vs_[(nt * 16 + l15) * 64 + ((ks * 32 + l4 * 8) ^ swz)]);
      __builtin_amdgcn_s_setprio(1);
#pragma unroll
      for (int g = 0; g < 2; ++g) {
#pragma unroll
        for (int nt = 0; nt < 4; ++nt)
          o[g][nt] = __builtin_amdgcn_mfma_f32_16x16x32_bf16(ae[g], bv[nt], o[g][nt], 0, 0, 0);
        dsum[g] = __builtin_amdgcn_mfma_f32_16x16x32_bf16(ae[g], b1, dsum[g], 0, 0, 0);
      }
      __builtin_amdgcn_s_setprio(0);
    }

    vmcnt0_barrier();   // next KV tile landed, all waves done with cur
    cur ^= 1;
  }

  // store UNNORMALIZED partials. o D-layout: row q local = l4*4+j (group g),
  // col d = nt*16+l15. dsum rows identical across l15 -> l15==0 writes.
  u16* Op = P + (size_t)split * PSPLIT_ELEMS;
#pragma unroll
  for (int g = 0; g < 2; ++g) {
    const int qg = q0 + g * 16 + l4 * 4;
#pragma unroll
    for (int nt = 0; nt < 4; ++nt)
#pragma unroll
      for (int j = 0; j < 4; ++j)
        Op[((size_t)h * S_LEN + qg + j) * 64 + nt * 16 + l15] = f2b(o[g][nt][j]);
    if (l15 == 0) {
#pragma unroll
      for (int j = 0; j < 4; ++j)
        DN[(size_t)(split * 32 + h) * S_LEN + qg + j] = dsum[g][j];
    }
  }
}

// ---------------- combine partials: attn = (o0+o1)/(d0+d1+1) ----------------
__global__ __launch_bounds__(256) void combine_kernel(
    const u16* __restrict__ P, const float* __restrict__ DN,
    u16* __restrict__ A)
{
  const int idx = blockIdx.x * 256 + threadIdx.x;   // 0..524287
  const int oct = idx & 7;            // 8 d-elems per thread
  const int q   = (idx >> 3) & 2047;
  const int h   = idx >> 14;
  const size_t po = ((size_t)h * S_LEN + q) * 64 + (oct << 3);
  const bf16x8 a = *(const bf16x8*)(P + po);
  const bf16x8 b = *(const bf16x8*)(P + PSPLIT_ELEMS + po);
  const float r = 1.0f / (DN[(size_t)h * S_LEN + q] +
                          DN[(size_t)(h + 32) * S_LEN + q] + 1.0f);
  u16 out[8];
#pragma unroll
  for (int e = 0; e < 8; ++e)
    out[e] = f2b(((float)a[e] + (float)b[e]) * r);
  *(uint4*)(A + (size_t)q * D_MODEL + h * 64 + (oct << 3)) = *(uint4*)out;
}

// ---------------------------------------------------------------------------
extern "C" void kernel_launch(void* const* d_in, const int* in_sizes, int n_in,
                              void* d_out, int out_size, void* d_ws, size_t ws_size,
                              hipStream_t stream) {
  const float* x  = (const float*)d_in[0];
  const float* pm = (const float*)d_in[1];
  const float* Wq = (const float*)d_in[2];
  const float* Wk = (const float*)d_in[3];
  const float* Wv = (const float*)d_in[4];
  const float* Wo = (const float*)d_in[5];
  float* outp = (float*)d_out;
  char* ws = (char*)d_ws;

  const size_t MB = 1024 * 1024;
  u16* xb   = (u16*)(ws + 0 * MB);    // x bf16             [2048][2048]  8MB
  u16* wqb  = (u16*)(ws + 8 * MB);    // Wq bf16 (wqkv[0])  [2048][2048]  8MB
  u16* wkb  = (u16*)(ws + 16 * MB);   // Wk bf16 (wqkv[1])  [512][2048]   2MB
  u16* wvb  = (u16*)(ws + 18 * MB);   // Wv bf16 (wqkv[2])  [512][2048]   2MB
  u16* wob  = (u16*)(ws + 20 * MB);   // Wo bf16            [2048][2048]  8MB
  u16* qro  = (u16*)(ws + 28 * MB);   // rope(xq)*CEXP bf16 [2048][2048]  8MB
  u16* kro  = (u16*)(ws + 36 * MB);   // rope(xk) bf16      [2048][512]   2MB
  u16* xvt  = (u16*)(ws + 40 * MB);   // xv^T bf16          [512][2048]   2MB
  u16* attn = (u16*)(ws + 42 * MB);   // attn out bf16      [2048][2048]  8MB
  const u16* wqkv = wqb;              // contiguous [3072][2048]
  // partials REUSE dead regions (xb/wqb/wkb are consumed by the QKV GEMM
  // which completes before attn_kernel starts):
  u16*   pPart = (u16*)(ws + 0 * MB);   // [2][32][2048][64] bf16, 16 MB
  float* dnb   = (float*)(ws + 16 * MB);// [2][32][2048] f32, 512 KB

  cast_all_kernel<<<14336, 256, 0, stream>>>(x, Wq, Wk, Wv, Wo, xb, wqb, wkb, wvb, wob);
  // fused QKV projection (N = 2048 Q + 512 K + 512 V); rope epilogues fused;
  // V written transposed directly (no separate transpose kernel)
  gemm_bt<1><<<dim3(24, 32), 256, 0, stream>>>(xb, wqkv, (void*)qro, (void*)kro,
                                               (void*)xvt, 2048, 3072, 2048, pm);
  // fused attention, KV-split x2 (partials; exp has no max-subtraction so
  // partials combine linearly)
  attn_kernel<<<dim3(16, 32, 2), 256, 0, stream>>>(qro, kro, xvt, pPart, dnb);
  combine_kernel<<<2048, 256, 0, stream>>>(pPart, dnb, attn);
  // output projection, fp32 out
  gemm_bt<2><<<dim3(16, 32), 256, 0, stream>>>(attn, wob, (void*)outp, nullptr,
                                               nullptr, 2048, 2048, 2048, nullptr);
}

// Round 15
// 133.816 us; speedup vs baseline: 1.0521x; 1.0521x over previous
//
#include <hip/hip_runtime.h>
#include <cmath>

typedef unsigned short u16;
typedef unsigned int u32;
typedef __bf16 bf16x8 __attribute__((ext_vector_type(8)));
typedef __bf16 bf16x4 __attribute__((ext_vector_type(4)));
typedef float f32x4 __attribute__((ext_vector_type(4)));

#define S_LEN 2048
#define D_MODEL 2048
#define DK_ 512
#define PM1_OFF 4194304   // offset of pm[1] in floats (1*1*2048*2048)
#define CEXP 0.06375872f  // (1/(sqrt(512)+1e-6)) * log2(e), folded into Q

__device__ __forceinline__ u16 f2b(float f) {
  u32 u = __float_as_uint(f);
  return (u16)((u + 0x7fffu + ((u >> 16) & 1u)) >> 16);
}

__device__ __forceinline__ void gload_lds16(const void* gp, void* lp) {
  __builtin_amdgcn_global_load_lds(
      (const __attribute__((address_space(1))) void*)gp,
      (__attribute__((address_space(3))) void*)lp, 16, 0, 0);
}

// ---------------- fused fp32 -> bf16 cast of x, Wq, Wk, Wv, Wo ----------------
__global__ __launch_bounds__(256) void cast_all_kernel(
    const float* __restrict__ x, const float* __restrict__ wq,
    const float* __restrict__ wk, const float* __restrict__ wv,
    const float* __restrict__ wo,
    u16* __restrict__ xb, u16* __restrict__ wqb, u16* __restrict__ wkb,
    u16* __restrict__ wvb, u16* __restrict__ wob)
{
  long i4 = (long)blockIdx.x * 256 + threadIdx.x;  // vec4 index
  const float* src; u16* dst; long off;
  if (i4 < 1048576)       { src = x;  dst = xb;  off = i4; }
  else if (i4 < 2097152)  { src = wq; dst = wqb; off = i4 - 1048576; }
  else if (i4 < 2359296)  { src = wk; dst = wkb; off = i4 - 2097152; }
  else if (i4 < 2621440)  { src = wv; dst = wvb; off = i4 - 2359296; }
  else                    { src = wo; dst = wob; off = i4 - 2621440; }
  float4 v = *(const float4*)(src + off * 4);
  ushort4 o;
  o.x = f2b(v.x); o.y = f2b(v.y); o.z = f2b(v.z); o.w = f2b(v.w);
  *(ushort4*)(dst + off * 4) = o;
}

// ---------------- GEMM: C = A @ B^T.  A[M,K], B[N,K] bf16 row-major ----------
// Tile 64x128, BK=64, 4 waves, T2 both-sides swizzle (conflicts==0), T1
// XCD-chunked remap. NEW (T4): two-barrier COUNTED-vmcnt phase — per K-tile:
//   stage(t+1) -> vmcnt(6) [waits only tile t's 6 loads; t+1's stay in
//   flight] -> s_barrier -> ds_read+MFMA(t) -> s_barrier.
// The barrier never drains VMEM; tile t's loads get a full iteration of cover
// (vs one compute phase with the old vmcnt(0)-before-barrier drain).
// EPI 1: fused QKV epilogue; EPI 2: plain fp32 store.
template<int EPI>
__global__ __launch_bounds__(256) void gemm_bt(
    const u16* __restrict__ A, const u16* __restrict__ B,
    void* __restrict__ C0, void* __restrict__ C1, void* __restrict__ C2,
    int M, int N, int K, const float* __restrict__ pm)
{
  __shared__ u16 As[2][64 * 64];
  __shared__ u16 Bs[2][128 * 64];
  const int tid = threadIdx.x;
  const int lane = tid & 63, w = tid >> 6;
  const int wr = w >> 1, wc = w & 1;
  const int l15 = lane & 15, l4 = lane >> 4;

  // T1 XCD-chunked remap (gridDim.y == 32 == m-tiles in all uses)
  const int nwg = gridDim.x * gridDim.y;
  const int orig = blockIdx.y * gridDim.x + blockIdx.x;
  const int lin2 = (orig & 7) * (nwg >> 3) + (orig >> 3);
  const int m0 = (lin2 & 31) * 64;       // m-tile fastest within XCD chunk
  const int n0 = (lin2 >> 5) * 128;

  // staging: 256 threads x 16B = 4 KB/issue = 32 rows of 64 u16.
  const int srow = tid >> 3;                        // 0..31
  const int scol = ((tid & 7) ^ (srow & 7)) << 3;   // inverse-swizzled src col
  const int swz = (l15 & 7) << 3;                   // u16 XOR for frag reads
  const int ldsoff = (tid >> 6) << 10;              // wave-uniform base
  const u16* gA = A + (size_t)(m0 + srow) * K + scol;
  const u16* gB = B + (size_t)(n0 + srow) * K + scol;

  const f32x4 z4 = {0.f, 0.f, 0.f, 0.f};
  f32x4 acc[2][4];
#pragma unroll
  for (int i = 0; i < 2; ++i)
#pragma unroll
    for (int j = 0; j < 4; ++j) acc[i][j] = z4;

  // prologue: stage tile 0, confirm
  {
    char* la = (char*)As[0] + ldsoff;
    char* lb = (char*)Bs[0] + ldsoff;
#pragma unroll
    for (int i = 0; i < 2; ++i) gload_lds16(gA + (size_t)(i * 32) * K, la + i * 4096);
#pragma unroll
    for (int i = 0; i < 4; ++i) gload_lds16(gB + (size_t)(i * 32) * K, lb + i * 4096);
  }
  asm volatile("s_waitcnt vmcnt(0)" ::: "memory");
  asm volatile("s_barrier" ::: "memory");

  const int NT = K >> 6;
  int cur = 0;
  for (int t = 0; t < NT; ++t) {
    if (t + 1 < NT) {   // stage next tile; wait ONLY for tile t (counted)
      const int kt = (t + 1) << 6;
      char* la = (char*)As[cur ^ 1] + ldsoff;
      char* lb = (char*)Bs[cur ^ 1] + ldsoff;
#pragma unroll
      for (int i = 0; i < 2; ++i) gload_lds16(gA + (size_t)(i * 32) * K + kt, la + i * 4096);
#pragma unroll
      for (int i = 0; i < 4; ++i) gload_lds16(gB + (size_t)(i * 32) * K + kt, lb + i * 4096);
      asm volatile("s_waitcnt vmcnt(6)" ::: "memory");
    } else {
      asm volatile("s_waitcnt vmcnt(0)" ::: "memory");
    }
    asm volatile("s_barrier" ::: "memory");   // all waves see tile t complete

    const u16* as = As[cur];
    const u16* bs = Bs[cur];
#pragma unroll
    for (int ks = 0; ks < 2; ++ks) {
      bf16x8 a[2], b[4];
#pragma unroll
      for (int mt = 0; mt < 2; ++mt)
        a[mt] = *(const bf16x8*)(&as[(wr * 32 + mt * 16 + l15) * 64 + ((ks * 32 + l4 * 8) ^ swz)]);
#pragma unroll
      for (int nt = 0; nt < 4; ++nt)
        b[nt] = *(const bf16x8*)(&bs[(wc * 64 + nt * 16 + l15) * 64 + ((ks * 32 + l4 * 8) ^ swz)]);
#pragma unroll
      for (int mt = 0; mt < 2; ++mt)
#pragma unroll
        for (int nt = 0; nt < 4; ++nt)
          acc[mt][nt] = __builtin_amdgcn_mfma_f32_16x16x32_bf16(a[mt], b[nt], acc[mt][nt], 0, 0, 0);
    }
    asm volatile("s_barrier" ::: "memory");   // all reads of cur done -> next
    cur ^= 1;                                 // iter may overwrite it
  }

#pragma unroll
  for (int mt = 0; mt < 2; ++mt)
#pragma unroll
    for (int nt = 0; nt < 4; ++nt) {
      const int mb = m0 + wr * 32 + mt * 16 + l4 * 4;   // base m (j = 0..3)
      const int n = n0 + wc * 64 + nt * 16 + l15;
      if (EPI == 2) {
#pragma unroll
        for (int j = 0; j < 4; ++j)
          ((float*)C0)[(size_t)(mb + j) * N + n] = acc[mt][nt][j];
      } else if (n >= 2560) {        // V range: write transposed -> xvt[c][m]
        const int c = n - 2560;
        ushort4 q;
        q.x = f2b(acc[mt][nt][0]); q.y = f2b(acc[mt][nt][1]);
        q.z = f2b(acc[mt][nt][2]); q.w = f2b(acc[mt][nt][3]);
        *(ushort4*)((u16*)C2 + (size_t)c * S_LEN + mb) = q;
      } else if (n < 2048) {         // Q range, rope d=2048, fold CEXP
        const int jj = (n < 1024) ? (n + 1024) : (n - 1024);
#pragma unroll
        for (int j = 0; j < 4; ++j) {
          const int m = mb + j;
          const float sv = (n < 1024) ? acc[mt][nt][j] : -acc[mt][nt][j];
          const float p = pm[(size_t)m * D_MODEL + jj] +
                          pm[PM1_OFF + (size_t)m * D_MODEL + jj];
          ((u16*)C0)[(size_t)m * D_MODEL + jj] = f2b(sv * p * CEXP);
        }
      } else {                       // K range, rope d=512
        const int nn = n - 2048;
        const int jj = (nn < 256) ? (nn + 256) : (nn - 256);
#pragma unroll
        for (int j = 0; j < 4; ++j) {
          const int m = mb + j;
          const float sv = (nn < 256) ? acc[mt][nt][j] : -acc[mt][nt][j];
          const float p = pm[(size_t)m * D_MODEL + jj] +
                          pm[PM1_OFF + (size_t)m * D_MODEL + jj];
          ((u16*)C1)[(size_t)m * DK_ + jj] = f2b(sv * p);
        }
      }
    }
}

// ---------------- fused attention (swapped QK^T, 32 q-rows/wave) -------------
// r12 structure (proven 61 us, full KV per block) + T4 two-barrier counted
// vmcnt(4): stage(t+1) -> vmcnt(4) -> barrier -> QK/exp/PV(t) -> barrier.
// Grid (16,32) = 512 blocks, XCD-chunked remap (4 heads x 16 q-blocks/XCD).
__global__ __launch_bounds__(256) void attn_kernel(
    const u16* __restrict__ Q, const u16* __restrict__ Kx,
    const u16* __restrict__ Vt, u16* __restrict__ O)
{
  __shared__ u16 Ks[2][64 * 64];     // K tile [t][hd] swizzled, dbuf (16 KB)
  __shared__ u16 Vs[2][64 * 64];     // V^T tile [hd][t] swizzled, dbuf (16 KB)
  __shared__ u16 Es[4 * 32 * 64];    // per-wave P tile [q][t] swizzled (16 KB)

  const int tid = threadIdx.x;
  const int lane = tid & 63, w = tid >> 6;
  const int l15 = lane & 15, l4 = lane >> 4;

  // T1 XCD-chunked remap: h-major, q-block fastest (512 blocks, 64/XCD)
  const int orig = blockIdx.y * 16 + blockIdx.x;
  const int lin2 = (orig & 7) * 64 + (orig >> 3);
  const int h = lin2 >> 4;
  const int qb = lin2 & 15;
  const int q0 = qb * 128 + w * 32;  // wave's 32-row base
  const int hk = (h & 7) * 64;       // kv column base (GQA: kv head = h%8)

  // Q as B-operand, two 16-row groups: row q = q0 + g*16 + l15
  bf16x8 bq[2][2];
#pragma unroll
  for (int g = 0; g < 2; ++g)
#pragma unroll
    for (int ks = 0; ks < 2; ++ks)
      bq[g][ks] = *(const bf16x8*)(Q + (size_t)(q0 + g * 16 + l15) * D_MODEL
                                     + h * 64 + ks * 32 + l4 * 8);

  bf16x8 b1;   // all-ones B fragment for the denominator MFMA
#pragma unroll
  for (int i = 0; i < 8; ++i) b1[i] = (__bf16)1.0f;

  const f32x4 z4 = {0.f, 0.f, 0.f, 0.f};
  f32x4 o[2][4], dsum[2];
#pragma unroll
  for (int g = 0; g < 2; ++g) {
    dsum[g] = z4;
#pragma unroll
    for (int nt = 0; nt < 4; ++nt) o[g][nt] = z4;
  }

  u16* Ew = Es + w * (32 * 64);
  const int swz = (l15 & 7) << 3;                    // u16 XOR for frag reads
  const int srow = tid >> 3;                         // staging row 0..31
  const int scol = ((tid & 7) ^ (srow & 7)) << 3;    // inverse-swizzled src col
  const int ldsoff = w << 10;                        // wave-uniform LDS base
  const u16* gK = Kx + (size_t)srow * DK_ + hk + scol;
  const u16* gV = Vt + (size_t)(hk + srow) * S_LEN + scol;

  // prologue: stage tile 0, confirm
  {
    char* lK = (char*)Ks[0] + ldsoff;
    char* lV = (char*)Vs[0] + ldsoff;
    gload_lds16(gK,                        lK);
    gload_lds16(gK + (size_t)32 * DK_,     lK + 4096);
    gload_lds16(gV,                        lV);
    gload_lds16(gV + (size_t)32 * S_LEN,   lV + 4096);
  }
  asm volatile("s_waitcnt vmcnt(0)" ::: "memory");
  asm volatile("s_barrier" ::: "memory");

  int cur = 0;
  for (int t0 = 0; t0 < S_LEN; t0 += 64) {
    if (t0 + 64 < S_LEN) {  // stage next KV tile; counted wait for tile t only
      char* lK = (char*)Ks[cur ^ 1] + ldsoff;
      char* lV = (char*)Vs[cur ^ 1] + ldsoff;
      gload_lds16(gK + (size_t)(t0 + 64) * DK_,       lK);
      gload_lds16(gK + (size_t)(t0 + 96) * DK_,       lK + 4096);
      gload_lds16(gV + t0 + 64,                       lV);
      gload_lds16(gV + t0 + 64 + (size_t)32 * S_LEN,  lV + 4096);
      asm volatile("s_waitcnt vmcnt(4)" ::: "memory");
    } else {
      asm volatile("s_waitcnt vmcnt(0)" ::: "memory");
    }
    asm volatile("s_barrier" ::: "memory");   // all waves see tile t complete

    const u16* ks_ = Ks[cur];
    const u16* vs_ = Vs[cur];

    // swapped QK^T: sT[g][tf] = K-rows x Q-rows(group g); ak read ONCE per ks
    f32x4 sT[2][4];
#pragma unroll
    for (int g = 0; g < 2; ++g)
#pragma unroll
      for (int tf = 0; tf < 4; ++tf) sT[g][tf] = z4;
#pragma unroll
    for (int ks = 0; ks < 2; ++ks) {
      bf16x8 ak[4];
#pragma unroll
      for (int tf = 0; tf < 4; ++tf)
        ak[tf] = *(const bf16x8*)(&ks_[(tf * 16 + l15) * 64 + ((ks * 32 + l4 * 8) ^ swz)]);
      __builtin_amdgcn_s_setprio(1);
#pragma unroll
      for (int g = 0; g < 2; ++g)
#pragma unroll
        for (int tf = 0; tf < 4; ++tf)
          sT[g][tf] = __builtin_amdgcn_mfma_f32_16x16x32_bf16(ak[tf], bq[g][ks], sT[g][tf], 0, 0, 0);
      __builtin_amdgcn_s_setprio(0);
    }

    // exp (raw v_exp_f32) + packed P staging. lane holds q = q0+g*16+l15;
    // t = tf*16 + l4*4 + j. Row (g*16+l15) swizzle uses (l15&7) — same XOR.
#pragma unroll
    for (int g = 0; g < 2; ++g)
#pragma unroll
      for (int tf = 0; tf < 4; ++tf) {
        const float e0 = __builtin_amdgcn_exp2f(sT[g][tf][0]);
        const float e1 = __builtin_amdgcn_exp2f(sT[g][tf][1]);
        const float e2 = __builtin_amdgcn_exp2f(sT[g][tf][2]);
        const float e3 = __builtin_amdgcn_exp2f(sT[g][tf][3]);
        bf16x4 pk = {(__bf16)e0, (__bf16)e1, (__bf16)e2, (__bf16)e3};
        *(bf16x4*)(&Ew[(g * 16 + l15) * 64 + ((tf * 16 + l4 * 4) ^ swz)]) = pk;
      }

    // PV: o[g][nt] += P[q,t] @ V[t,hd]; dsum[g] += P @ ones.
#pragma unroll
    for (int ks = 0; ks < 2; ++ks) {
      bf16x8 ae[2], bv[4];
#pragma unroll
      for (int g = 0; g < 2; ++g)
        ae[g] = *(const bf16x8*)(&Ew[(g * 16 + l15) * 64 + ((ks * 32 + l4 * 8) ^ swz)]);
#pragma unroll
      for (int nt = 0; nt < 4; ++nt)
        bv[nt] = *(const bf16x8*)(&vs_[(nt * 16 + l15) * 64 + ((ks * 32 + l4 * 8) ^ swz)]);
      __builtin_amdgcn_s_setprio(1);
#pragma unroll
      for (int g = 0; g < 2; ++g) {
#pragma unroll
        for (int nt = 0; nt < 4; ++nt)
          o[g][nt] = __builtin_amdgcn_mfma_f32_16x16x32_bf16(ae[g], bv[nt], o[g][nt], 0, 0, 0);
        dsum[g] = __builtin_amdgcn_mfma_f32_16x16x32_bf16(ae[g], b1, dsum[g], 0, 0, 0);
      }
      __builtin_amdgcn_s_setprio(0);
    }

    asm volatile("s_barrier" ::: "memory");   // all reads of cur done
    cur ^= 1;
  }

  // normalize + store. o D-layout: row q local = l4*4+j (within group g),
  // col d = nt*16+l15. dsum rows identical -> no shuffles.
#pragma unroll
  for (int g = 0; g < 2; ++g) {
    float dn[4];
#pragma unroll
    for (int j = 0; j < 4; ++j) dn[j] = dsum[g][j] + 1.0f;
#pragma unroll
    for (int nt = 0; nt < 4; ++nt)
#pragma unroll
      for (int j = 0; j < 4; ++j) {
        O[(size_t)(q0 + g * 16 + l4 * 4 + j) * D_MODEL + h * 64 + nt * 16 + l15] =
            f2b(o[g][nt][j] / dn[j]);
      }
  }
}

// ---------------------------------------------------------------------------
extern "C" void kernel_launch(void* const* d_in, const int* in_sizes, int n_in,
                              void* d_out, int out_size, void* d_ws, size_t ws_size,
                              hipStream_t stream) {
  const float* x  = (const float*)d_in[0];
  const float* pm = (const float*)d_in[1];
  const float* Wq = (const float*)d_in[2];
  const float* Wk = (const float*)d_in[3];
  const float* Wv = (const float*)d_in[4];
  const float* Wo = (const float*)d_in[5];
  float* outp = (float*)d_out;
  char* ws = (char*)d_ws;

  const size_t MB = 1024 * 1024;
  u16* xb   = (u16*)(ws + 0 * MB);    // x bf16             [2048][2048]  8MB
  u16* wqb  = (u16*)(ws + 8 * MB);    // Wq bf16 (wqkv[0])  [2048][2048]  8MB
  u16* wkb  = (u16*)(ws + 16 * MB);   // Wk bf16 (wqkv[1])  [512][2048]   2MB
  u16* wvb  = (u16*)(ws + 18 * MB);   // Wv bf16 (wqkv[2])  [512][2048]   2MB
  u16* wob  = (u16*)(ws + 20 * MB);   // Wo bf16            [2048][2048]  8MB
  u16* qro  = (u16*)(ws + 28 * MB);   // rope(xq)*CEXP bf16 [2048][2048]  8MB
  u16* kro  = (u16*)(ws + 36 * MB);   // rope(xk) bf16      [2048][512]   2MB
  u16* xvt  = (u16*)(ws + 40 * MB);   // xv^T bf16          [512][2048]   2MB
  u16* attn = (u16*)(ws + 42 * MB);   // attn out bf16      [2048][2048]  8MB
  const u16* wqkv = wqb;              // contiguous [3072][2048]

  cast_all_kernel<<<14336, 256, 0, stream>>>(x, Wq, Wk, Wv, Wo, xb, wqb, wkb, wvb, wob);
  // fused QKV projection (N = 2048 Q + 512 K + 512 V); rope epilogues fused;
  // V written transposed directly (no separate transpose kernel)
  gemm_bt<1><<<dim3(24, 32), 256, 0, stream>>>(xb, wqkv, (void*)qro, (void*)kro,
                                               (void*)xvt, 2048, 3072, 2048, pm);
  // fused attention (32 q/wave, 128 q/block, full KV per block)
  attn_kernel<<<dim3(16, 32), 256, 0, stream>>>(qro, kro, xvt, attn);
  // output projection, fp32 out
  gemm_bt<2><<<dim3(16, 32), 256, 0, stream>>>(attn, wob, (void*)outp, nullptr,
                                               nullptr, 2048, 2048, 2048, nullptr);
}